// Round 1
// 962.938 us; speedup vs baseline: 1.0754x; 1.0754x over previous
//
#include <hip/hip_runtime.h>

// ---------------------------------------------------------------------------
// MultiHeadAttention (fp32 I/O, bf16 MFMA compute):
//   LN -> {Q,K,V} proj -> softmax(QK^T/8 + pos, mask) -> attn (materialized,
//   fp32, part of d_out) -> PV -> out proj.
// B=4 H=8 S=2048 D=512 DK=64.  d_out = [out (B,S,D) | attn (B,H,S,S)] fp32.
// ---------------------------------------------------------------------------

typedef __bf16 bf16;
typedef __attribute__((ext_vector_type(8))) __bf16 bfv8;   // 16 B MFMA frag
typedef __attribute__((ext_vector_type(4))) __bf16 bfv4;   // 8 B
typedef __attribute__((ext_vector_type(2))) __bf16 bfv2;   // 4 B
typedef __attribute__((ext_vector_type(4))) float  f32x4;  // MFMA acc / 16 B
typedef __attribute__((ext_vector_type(2))) float  f32x2;  // 8 B

static constexpr int Dm = 512, Hh = 8, Sq = 2048, Bb = 4;
static constexpr int BS = Bb * Sq;                 // 8192 rows

__device__ __forceinline__ f32x4 mfma16(bfv8 a, bfv8 b, f32x4 c) {
  return __builtin_amdgcn_mfma_f32_16x16x32_bf16(a, b, c, 0, 0, 0);
}

// ---------------- K0: posT[j][i] = mask[i][j] ? pos[i][j] : -1e30 ------------
__global__ __launch_bounds__(256) void posT_kernel(
    const float* __restrict__ pos, const int* __restrict__ mask,
    float* __restrict__ posT) {
  __shared__ float tile[32][33];
  int i0 = blockIdx.y * 32, j0 = blockIdx.x * 32;
  int tx = threadIdx.x & 31, ty = threadIdx.x >> 5;  // 32 x 8
#pragma unroll
  for (int rr = 0; rr < 32; rr += 8) {
    int i = i0 + ty + rr, j = j0 + tx;
    float pv = pos[(size_t)i * Sq + j];
    int   mv = mask[(size_t)i * Sq + j];
    tile[ty + rr][tx] = mv ? pv : -1e30f;
  }
  __syncthreads();
#pragma unroll
  for (int rr = 0; rr < 32; rr += 8) {
    int j = j0 + ty + rr, i = i0 + tx;
    posT[(size_t)j * Sq + i] = tile[tx][ty + rr];
  }
}

// ---------------- K1: LayerNorm (wave per row of 512), fp32 -> bf16 ----------
__global__ __launch_bounds__(256) void ln_kernel(
    const float* __restrict__ q, const float* __restrict__ k,
    const float* __restrict__ v, const float* __restrict__ w,
    const float* __restrict__ bia, bf16* __restrict__ qn,
    bf16* __restrict__ kn, bf16* __restrict__ vn) {
  int wv = threadIdx.x >> 6, lane = threadIdx.x & 63;
  int row = blockIdx.x * 4 + wv;  // 0..8191
  int which = blockIdx.y;
  const float* src = which == 0 ? q : (which == 1 ? k : v);
  bf16* dst        = which == 0 ? qn : (which == 1 ? kn : vn);

  f32x4 x0 = *(const f32x4*)(src + (size_t)row * Dm + lane * 8);
  f32x4 x1 = *(const f32x4*)(src + (size_t)row * Dm + lane * 8 + 4);
  float xf[8], s1 = 0.f, s2 = 0.f;
#pragma unroll
  for (int i = 0; i < 4; i++) { xf[i] = x0[i]; xf[4 + i] = x1[i]; }
#pragma unroll
  for (int i = 0; i < 8; i++) { s1 += xf[i]; s2 += xf[i] * xf[i]; }
#pragma unroll
  for (int m = 1; m < 64; m <<= 1) { s1 += __shfl_xor(s1, m, 64); s2 += __shfl_xor(s2, m, 64); }
  float mu = s1 * (1.0f / 512.0f);
  float var = s2 * (1.0f / 512.0f) - mu * mu;
  float rs = rsqrtf(var + 1e-5f);
  f32x4 w0 = *(const f32x4*)(w + lane * 8);
  f32x4 w1 = *(const f32x4*)(w + lane * 8 + 4);
  f32x4 b0 = *(const f32x4*)(bia + lane * 8);
  f32x4 b1 = *(const f32x4*)(bia + lane * 8 + 4);
  bfv8 o;
#pragma unroll
  for (int i = 0; i < 4; i++) {
    o[i]     = (bf16)((xf[i] - mu) * rs * w0[i] + b0[i]);
    o[4 + i] = (bf16)((xf[4 + i] - mu) * rs * w1[i] + b1[i]);
  }
  *(bfv8*)(dst + (size_t)row * Dm + lane * 8) = o;
}

// ---------------- K2/K4: C[m,n] = sum_k A[m,k]*W[n,k] + bias[n] --------------
// A bf16 [M,512], W fp32 [N=512,512].  M=8192.
// mode 0: bf16 qh/kh [B,H,S,DK]; 1: bf16 vT [B,H,DK,S]; 2: fp32 out [M,512].
__global__ __launch_bounds__(256) void gemm_bt(
    const bf16* __restrict__ A, const float* __restrict__ W,
    const float* __restrict__ bias, bf16* __restrict__ outb,
    float* __restrict__ outf, int mode) {
  __shared__ __align__(16) bf16 As[64][72];
  __shared__ __align__(16) bf16 Bs[64][72];
  int m0 = blockIdx.x * 64, n0 = blockIdx.y * 64;
  int tid = threadIdx.x;
  int wv = tid >> 6, lane = tid & 63;
  int wm = (wv & 1) * 32, wn = (wv >> 1) * 32;
  int r16 = lane & 15, quad = lane >> 4;
  int lr = tid >> 2, sc = (tid & 3) * 16;

  f32x4 acc[2][2] = {};
  const bf16*  Ap = A + (size_t)(m0 + lr) * 512 + sc;
  const float* Wp = W + (size_t)(n0 + lr) * 512 + sc;

  for (int k0 = 0; k0 < 512; k0 += 64) {
    bfv8 a0 = *(const bfv8*)(Ap + k0);
    bfv8 a1 = *(const bfv8*)(Ap + k0 + 8);
    f32x4 w0 = *(const f32x4*)(Wp + k0);
    f32x4 w1 = *(const f32x4*)(Wp + k0 + 4);
    f32x4 w2 = *(const f32x4*)(Wp + k0 + 8);
    f32x4 w3 = *(const f32x4*)(Wp + k0 + 12);
    bfv8 bb0, bb1;
#pragma unroll
    for (int i = 0; i < 4; i++) {
      bb0[i] = (bf16)w0[i]; bb0[4 + i] = (bf16)w1[i];
      bb1[i] = (bf16)w2[i]; bb1[4 + i] = (bf16)w3[i];
    }
    __syncthreads();
    *(bfv8*)&As[lr][sc] = a0;  *(bfv8*)&As[lr][sc + 8] = a1;
    *(bfv8*)&Bs[lr][sc] = bb0; *(bfv8*)&Bs[lr][sc + 8] = bb1;
    __syncthreads();
#pragma unroll
    for (int kk = 0; kk < 2; kk++) {
      bfv8 af0 = *(const bfv8*)&As[wm + r16][kk * 32 + quad * 8];
      bfv8 af1 = *(const bfv8*)&As[wm + 16 + r16][kk * 32 + quad * 8];
      bfv8 bf0 = *(const bfv8*)&Bs[wn + r16][kk * 32 + quad * 8];
      bfv8 bf1 = *(const bfv8*)&Bs[wn + 16 + r16][kk * 32 + quad * 8];
      acc[0][0] = mfma16(af0, bf0, acc[0][0]);
      acc[0][1] = mfma16(af0, bf1, acc[0][1]);
      acc[1][0] = mfma16(af1, bf0, acc[1][0]);
      acc[1][1] = mfma16(af1, bf1, acc[1][1]);
    }
  }

#pragma unroll
  for (int nt = 0; nt < 2; nt++) {
    int n = n0 + wn + nt * 16 + r16;
    float bb = bias[n];
#pragma unroll
    for (int mt = 0; mt < 2; mt++) {
#pragma unroll
      for (int r = 0; r < 4; r++) {
        int m = m0 + wm + mt * 16 + quad * 4 + r;
        float o = acc[mt][nt][r] + bb;
        int bb_ = m >> 11, s = m & 2047, hh = n >> 6, dd = n & 63;
        if (mode == 0)
          outb[(((size_t)(bb_ * Hh + hh)) * Sq + s) * 64 + dd] = (bf16)o;
        else if (mode == 1)
          outb[(((size_t)(bb_ * Hh + hh)) * 64 + dd) * Sq + s] = (bf16)o;
        else
          outf[(size_t)m * 512 + n] = o;
      }
    }
  }
}

// ---------------- K3: attention: 16 q-rows x one (b,h) per block -------------
// 8 waves x 256 columns each (acc[16] = 64 regs/lane) so VGPR+AGPR <= 128
// -> 4 waves/SIMD occupancy (was 2 with the 512-col / acc[32] layout).
__global__ __launch_bounds__(512, 4) void attn_kernel(
    const bf16* __restrict__ qh, const bf16* __restrict__ kh,
    const bf16* __restrict__ vT, const float* __restrict__ posT,
    float* __restrict__ attn, bf16* __restrict__ xout) {
  __shared__ float smax[8][16];
  __shared__ float ssum[8][16];
  __shared__ __align__(16) bf16 Pbuf[8][16][136];  // per-wave [16][128]+8 pad
  __shared__ __align__(16) float xred[8][16][64];

  const int tid = threadIdx.x;
  const int wv = tid >> 6, lane = tid & 63;
  const int r16 = lane & 15, quad = lane >> 4;
  const int strip = blockIdx.x, h = blockIdx.y, b = blockIdx.z;
  const int bh = b * Hh + h;
  const int r0 = strip * 16;
  const int c0 = wv * 256;                     // wave's 256-key chunk

  const bf16* qbase = qh + (size_t)bh * Sq * 64;
  const bf16* kbase = kh + (size_t)bh * Sq * 64;
  const bf16* vbase = vT + (size_t)bh * 64 * Sq;

  bfv8 aq0 = *(const bfv8*)(qbase + (size_t)(r0 + r16) * 64 + quad * 8);
  bfv8 aq1 = *(const bfv8*)(qbase + (size_t)(r0 + r16) * 64 + 32 + quad * 8);

  // ---- phase 1: raw scores (wave's 256 keys in 16 16x16 tiles) ----
  f32x4 acc[16];
#pragma unroll
  for (int t = 0; t < 16; t++) {
    const bf16* kp = kbase + (size_t)(c0 + t * 16 + r16) * 64 + quad * 8;
    bfv8 kb0 = *(const bfv8*)kp;
    bfv8 kb1 = *(const bfv8*)(kp + 32);
    f32x4 z = {0.f, 0.f, 0.f, 0.f};
    z = mfma16(aq0, kb0, z);
    z = mfma16(aq1, kb1, z);
    acc[t] = z;
  }

  // ---- phase 2: s = s/8 + pos; wave-local max ----
  float mx[4] = {-1e30f, -1e30f, -1e30f, -1e30f};
#pragma unroll
  for (int t = 0; t < 16; t++) {
    int colg = c0 + t * 16 + r16;
    f32x4 pk = *(const f32x4*)(posT + (size_t)colg * Sq + r0 + quad * 4);
#pragma unroll
    for (int r = 0; r < 4; r++) {
      float s = acc[t][r] * 0.125f + pk[r];
      acc[t][r] = s;
      mx[r] = fmaxf(mx[r], s);
    }
  }
#pragma unroll
  for (int m = 1; m < 16; m <<= 1)
#pragma unroll
    for (int r = 0; r < 4; r++) mx[r] = fmaxf(mx[r], __shfl_xor(mx[r], m, 64));

  // exp against the WAVE max; final rescale by exp(m_w - M)/S after one
  // combined (max,sum) LDS exchange -> single barrier instead of two.
  float sm[4] = {0.f, 0.f, 0.f, 0.f};
#pragma unroll
  for (int t = 0; t < 16; t++)
#pragma unroll
    for (int r = 0; r < 4; r++) {
      float e = __expf(acc[t][r] - mx[r]);
      acc[t][r] = e;
      sm[r] += e;
    }
#pragma unroll
  for (int m = 1; m < 16; m <<= 1)
#pragma unroll
    for (int r = 0; r < 4; r++) sm[r] += __shfl_xor(sm[r], m, 64);

  if (r16 == 0) {
#pragma unroll
    for (int r = 0; r < 4; r++) {
      smax[wv][quad * 4 + r] = mx[r];
      ssum[wv][quad * 4 + r] = sm[r];
    }
  }
  __syncthreads();

  float comb[4];
#pragma unroll
  for (int r = 0; r < 4; r++) {
    int row = quad * 4 + r;
    float M = smax[0][row];
#pragma unroll
    for (int w = 1; w < 8; w++) M = fmaxf(M, smax[w][row]);
    float S = 0.f;
#pragma unroll
    for (int w = 0; w < 8; w++) S += ssum[w][row] * __expf(smax[w][row] - M);
    comb[r] = __expf(mx[r] - M) / S;   // p = e * comb == exp(x - M) / S
  }

  // ---- phase 3: per 128-col chunk: fp32 attn store + bf16 repack + PV ----
  f32x4 xacc[4] = {};
#pragma unroll
  for (int c = 0; c < 2; c++) {
#pragma unroll
    for (int tt = 0; tt < 8; tt++) {
      int t = c * 8 + tt;
      int colg = c0 + t * 16 + r16;
#pragma unroll
      for (int r = 0; r < 4; r++) {
        float p = acc[t][r] * comb[r];
        Pbuf[wv][quad * 4 + r][tt * 16 + r16] = (bf16)p;
        // write-once 512 MiB stream: keep it out of L2 (K/V/posT live there)
        __builtin_nontemporal_store(
            p, attn + ((size_t)bh * Sq + r0 + quad * 4 + r) * Sq + colg);
      }
    }
    // PV: x[16,64] += P[16,128] @ V[128,64]   (wave-private Pbuf, no barrier)
#pragma unroll
    for (int ks = 0; ks < 4; ks++) {
      bfv8 af = *(const bfv8*)&Pbuf[wv][r16][ks * 32 + quad * 8];
      int key0 = c0 + c * 128 + ks * 32;
#pragma unroll
      for (int nt = 0; nt < 4; nt++) {
        bfv8 bvv = *(const bfv8*)(vbase + (size_t)(nt * 16 + r16) * Sq + key0 + quad * 8);
        xacc[nt] = mfma16(af, bvv, xacc[nt]);
      }
    }
  }

  // ---- cross-wave x reduction -> x[B,S,D] (bf16 for the final GEMM) ----
#pragma unroll
  for (int nt = 0; nt < 4; nt++)
#pragma unroll
    for (int r = 0; r < 4; r++)
      xred[wv][quad * 4 + r][nt * 16 + r16] = xacc[nt][r];
  __syncthreads();
  {
    int row = tid >> 5, d2 = (tid & 31) * 2;   // 512 thr: 16 rows x 32 pairs
    f32x2 s = {0.f, 0.f};
#pragma unroll
    for (int w = 0; w < 8; w++) s += *(const f32x2*)&xred[w][row][d2];
    bfv2 o;
    o[0] = (bf16)s[0];
    o[1] = (bf16)s[1];
    *(bfv2*)(xout + ((size_t)(b * Sq + r0 + row)) * 512 + h * 64 + d2) = o;
  }
}

// ---------------------------------------------------------------------------
extern "C" void kernel_launch(void* const* d_in, const int* in_sizes, int n_in,
                              void* d_out, int out_size, void* d_ws,
                              size_t ws_size, hipStream_t stream) {
  const float* q    = (const float*)d_in[0];
  const float* k    = (const float*)d_in[1];
  const float* v    = (const float*)d_in[2];
  const int*   mask = (const int*)d_in[3];
  const float* pos  = (const float*)d_in[4];
  const float* lnw  = (const float*)d_in[5];
  const float* lnb  = (const float*)d_in[6];
  const float* Wq   = (const float*)d_in[7];
  const float* bq   = (const float*)d_in[8];
  const float* Wk   = (const float*)d_in[9];
  const float* bk   = (const float*)d_in[10];
  const float* Wv   = (const float*)d_in[11];
  const float* bv   = (const float*)d_in[12];
  const float* Wo   = (const float*)d_in[13];
  const float* bo   = (const float*)d_in[14];

  const size_t NE = (size_t)Bb * Sq * Dm;  // 4,194,304 (== S*S)
  if (ws_size < 64ull * 1024 * 1024) return;  // need exactly 64 MiB scratch

  // ws layout (64 MiB total):
  //   [ 0,16) MiB  posT  fp32 [S,S]
  //   [16,24) MiB  qn    bf16 [8192,512]   (aliased by xbuf after use)
  //   [24,32) MiB  kn    bf16
  //   [32,40) MiB  vn    bf16
  //   [40,48) MiB  qhp   bf16 [B,H,S,DK]
  //   [48,56) MiB  khp   bf16 [B,H,S,DK]
  //   [56,64) MiB  vhT   bf16 [B,H,DK,S]
  char* wsb = (char*)d_ws;
  float* posT = (float*)wsb;
  bf16* qn   = (bf16*)(wsb + 16ull * 1024 * 1024);
  bf16* kn   = (bf16*)(wsb + 24ull * 1024 * 1024);
  bf16* vn   = (bf16*)(wsb + 32ull * 1024 * 1024);
  bf16* qhp  = (bf16*)(wsb + 40ull * 1024 * 1024);
  bf16* khp  = (bf16*)(wsb + 48ull * 1024 * 1024);
  bf16* vhT  = (bf16*)(wsb + 56ull * 1024 * 1024);
  bf16* xbuf = qn;  // qn is dead once the Q projection GEMM has run

  float* out  = (float*)d_out;
  float* attn = out + NE;

  posT_kernel<<<dim3(Sq / 32, Sq / 32), 256, 0, stream>>>(pos, mask, posT);
  ln_kernel<<<dim3(BS / 4, 3), 256, 0, stream>>>(q, k, v, lnw, lnb, qn, kn, vn);
  gemm_bt<<<dim3(BS / 64, Dm / 64), 256, 0, stream>>>(qn, Wq, bq, qhp, nullptr, 0);
  gemm_bt<<<dim3(BS / 64, Dm / 64), 256, 0, stream>>>(kn, Wk, bk, khp, nullptr, 0);
  gemm_bt<<<dim3(BS / 64, Dm / 64), 256, 0, stream>>>(vn, Wv, bv, vhT, nullptr, 1);
  attn_kernel<<<dim3(Sq / 16, Hh, Bb), 512, 0, stream>>>(qhp, khp, vhT, posT,
                                                         attn, xbuf);
  gemm_bt<<<dim3(BS / 64, Dm / 64), 256, 0, stream>>>(xbuf, Wo, bo, nullptr, out, 2);
}

// Round 2
// 947.386 us; speedup vs baseline: 1.0931x; 1.0164x over previous
//
#include <hip/hip_runtime.h>

// ---------------------------------------------------------------------------
// MultiHeadAttention (fp32 I/O, bf16 MFMA compute):
//   LN -> {Q,K,V} proj -> softmax(QK^T/8 + pos, mask) -> attn (materialized,
//   fp32, part of d_out) -> PV -> out proj.
// B=4 H=8 S=2048 D=512 DK=64.  d_out = [out (B,S,D) | attn (B,H,S,S)] fp32.
// ---------------------------------------------------------------------------

typedef __bf16 bf16;
typedef __attribute__((ext_vector_type(8))) __bf16 bfv8;   // 16 B MFMA frag
typedef __attribute__((ext_vector_type(4))) __bf16 bfv4;   // 8 B
typedef __attribute__((ext_vector_type(2))) __bf16 bfv2;   // 4 B
typedef __attribute__((ext_vector_type(4))) float  f32x4;  // MFMA acc / 16 B
typedef __attribute__((ext_vector_type(2))) float  f32x2;  // 8 B

static constexpr int Dm = 512, Hh = 8, Sq = 2048, Bb = 4;
static constexpr int BS = Bb * Sq;                 // 8192 rows

__device__ __forceinline__ f32x4 mfma16(bfv8 a, bfv8 b, f32x4 c) {
  return __builtin_amdgcn_mfma_f32_16x16x32_bf16(a, b, c, 0, 0, 0);
}

// ---------------- K0: posT[j][i] = mask[i][j] ? pos[i][j] : -1e30 ------------
__global__ __launch_bounds__(256) void posT_kernel(
    const float* __restrict__ pos, const int* __restrict__ mask,
    float* __restrict__ posT) {
  __shared__ float tile[32][33];
  int i0 = blockIdx.y * 32, j0 = blockIdx.x * 32;
  int tx = threadIdx.x & 31, ty = threadIdx.x >> 5;  // 32 x 8
#pragma unroll
  for (int rr = 0; rr < 32; rr += 8) {
    int i = i0 + ty + rr, j = j0 + tx;
    float pv = pos[(size_t)i * Sq + j];
    int   mv = mask[(size_t)i * Sq + j];
    tile[ty + rr][tx] = mv ? pv : -1e30f;
  }
  __syncthreads();
#pragma unroll
  for (int rr = 0; rr < 32; rr += 8) {
    int j = j0 + ty + rr, i = i0 + tx;
    posT[(size_t)j * Sq + i] = tile[tx][ty + rr];
  }
}

// ---------------- K1: LayerNorm (wave per row of 512), fp32 -> bf16 ----------
__global__ __launch_bounds__(256) void ln_kernel(
    const float* __restrict__ q, const float* __restrict__ k,
    const float* __restrict__ v, const float* __restrict__ w,
    const float* __restrict__ bia, bf16* __restrict__ qn,
    bf16* __restrict__ kn, bf16* __restrict__ vn) {
  int wv = threadIdx.x >> 6, lane = threadIdx.x & 63;
  int row = blockIdx.x * 4 + wv;  // 0..8191
  int which = blockIdx.y;
  const float* src = which == 0 ? q : (which == 1 ? k : v);
  bf16* dst        = which == 0 ? qn : (which == 1 ? kn : vn);

  f32x4 x0 = *(const f32x4*)(src + (size_t)row * Dm + lane * 8);
  f32x4 x1 = *(const f32x4*)(src + (size_t)row * Dm + lane * 8 + 4);
  float xf[8], s1 = 0.f, s2 = 0.f;
#pragma unroll
  for (int i = 0; i < 4; i++) { xf[i] = x0[i]; xf[4 + i] = x1[i]; }
#pragma unroll
  for (int i = 0; i < 8; i++) { s1 += xf[i]; s2 += xf[i] * xf[i]; }
#pragma unroll
  for (int m = 1; m < 64; m <<= 1) { s1 += __shfl_xor(s1, m, 64); s2 += __shfl_xor(s2, m, 64); }
  float mu = s1 * (1.0f / 512.0f);
  float var = s2 * (1.0f / 512.0f) - mu * mu;
  float rs = rsqrtf(var + 1e-5f);
  f32x4 w0 = *(const f32x4*)(w + lane * 8);
  f32x4 w1 = *(const f32x4*)(w + lane * 8 + 4);
  f32x4 b0 = *(const f32x4*)(bia + lane * 8);
  f32x4 b1 = *(const f32x4*)(bia + lane * 8 + 4);
  bfv8 o;
#pragma unroll
  for (int i = 0; i < 4; i++) {
    o[i]     = (bf16)((xf[i] - mu) * rs * w0[i] + b0[i]);
    o[4 + i] = (bf16)((xf[4 + i] - mu) * rs * w1[i] + b1[i]);
  }
  *(bfv8*)(dst + (size_t)row * Dm + lane * 8) = o;
}

// ---------------- shared GEMM body: C[m,n] = sum_k A[m,k]*W[n,k] + bias[n] ---
// A bf16 [M,512], W fp32 [N=512,512].  M=8192.
// mode 0: bf16 qh/kh [B,H,S,DK]; 1: bf16 vT [B,H,DK,S]; 2: fp32 out [M,512].
__device__ __forceinline__ void gemm_body(
    const bf16* __restrict__ A, const float* __restrict__ W,
    const float* __restrict__ bias, bf16* __restrict__ outb,
    float* __restrict__ outf, int mode, int m0, int n0) {
  __shared__ __align__(16) bf16 As[64][72];
  __shared__ __align__(16) bf16 Bs[64][72];
  int tid = threadIdx.x;
  int wv = tid >> 6, lane = tid & 63;
  int wm = (wv & 1) * 32, wn = (wv >> 1) * 32;
  int r16 = lane & 15, quad = lane >> 4;
  int lr = tid >> 2, sc = (tid & 3) * 16;

  f32x4 acc[2][2] = {};
  const bf16*  Ap = A + (size_t)(m0 + lr) * 512 + sc;
  const float* Wp = W + (size_t)(n0 + lr) * 512 + sc;

  for (int k0 = 0; k0 < 512; k0 += 64) {
    bfv8 a0 = *(const bfv8*)(Ap + k0);
    bfv8 a1 = *(const bfv8*)(Ap + k0 + 8);
    f32x4 w0 = *(const f32x4*)(Wp + k0);
    f32x4 w1 = *(const f32x4*)(Wp + k0 + 4);
    f32x4 w2 = *(const f32x4*)(Wp + k0 + 8);
    f32x4 w3 = *(const f32x4*)(Wp + k0 + 12);
    bfv8 bb0, bb1;
#pragma unroll
    for (int i = 0; i < 4; i++) {
      bb0[i] = (bf16)w0[i]; bb0[4 + i] = (bf16)w1[i];
      bb1[i] = (bf16)w2[i]; bb1[4 + i] = (bf16)w3[i];
    }
    __syncthreads();
    *(bfv8*)&As[lr][sc] = a0;  *(bfv8*)&As[lr][sc + 8] = a1;
    *(bfv8*)&Bs[lr][sc] = bb0; *(bfv8*)&Bs[lr][sc + 8] = bb1;
    __syncthreads();
#pragma unroll
    for (int kk = 0; kk < 2; kk++) {
      bfv8 af0 = *(const bfv8*)&As[wm + r16][kk * 32 + quad * 8];
      bfv8 af1 = *(const bfv8*)&As[wm + 16 + r16][kk * 32 + quad * 8];
      bfv8 bf0 = *(const bfv8*)&Bs[wn + r16][kk * 32 + quad * 8];
      bfv8 bf1 = *(const bfv8*)&Bs[wn + 16 + r16][kk * 32 + quad * 8];
      acc[0][0] = mfma16(af0, bf0, acc[0][0]);
      acc[0][1] = mfma16(af0, bf1, acc[0][1]);
      acc[1][0] = mfma16(af1, bf0, acc[1][0]);
      acc[1][1] = mfma16(af1, bf1, acc[1][1]);
    }
  }

#pragma unroll
  for (int nt = 0; nt < 2; nt++) {
    int n = n0 + wn + nt * 16 + r16;
    float bb = bias[n];
#pragma unroll
    for (int mt = 0; mt < 2; mt++) {
#pragma unroll
      for (int r = 0; r < 4; r++) {
        int m = m0 + wm + mt * 16 + quad * 4 + r;
        float o = acc[mt][nt][r] + bb;
        int bb_ = m >> 11, s = m & 2047, hh = n >> 6, dd = n & 63;
        if (mode == 0)
          outb[(((size_t)(bb_ * Hh + hh)) * Sq + s) * 64 + dd] = (bf16)o;
        else if (mode == 1)
          outb[(((size_t)(bb_ * Hh + hh)) * 64 + dd) * Sq + s] = (bf16)o;
        else
          outf[(size_t)m * 512 + n] = o;
      }
    }
  }
}

// ---- merged Q/K/V projection: blockIdx.z selects which projection ----------
__global__ __launch_bounds__(256) void gemm_proj(
    const bf16* __restrict__ qn, const bf16* __restrict__ kn,
    const bf16* __restrict__ vn, const float* __restrict__ Wq,
    const float* __restrict__ Wk, const float* __restrict__ Wv,
    const float* __restrict__ bq, const float* __restrict__ bk,
    const float* __restrict__ bv, bf16* __restrict__ qhp,
    bf16* __restrict__ khp, bf16* __restrict__ vhT) {
  int z = blockIdx.z;
  const bf16*  A    = z == 0 ? qn : (z == 1 ? kn : vn);
  const float* W    = z == 0 ? Wq : (z == 1 ? Wk : Wv);
  const float* bias = z == 0 ? bq : (z == 1 ? bk : bv);
  bf16*        outb = z == 0 ? qhp : (z == 1 ? khp : vhT);
  int mode = (z == 2) ? 1 : 0;
  gemm_body(A, W, bias, outb, nullptr, mode, blockIdx.x * 64, blockIdx.y * 64);
}

// ---- single GEMM (used for the output projection, mode 2) ------------------
__global__ __launch_bounds__(256) void gemm_bt(
    const bf16* __restrict__ A, const float* __restrict__ W,
    const float* __restrict__ bias, bf16* __restrict__ outb,
    float* __restrict__ outf, int mode) {
  gemm_body(A, W, bias, outb, outf, mode, blockIdx.x * 64, blockIdx.y * 64);
}

// ---------------- K3: attention: 16 q-rows x one (b,h) per block -------------
// 8 waves x 256 columns each (acc[16] = 64 regs/lane).
// Grid flattened to 1D with a bijective XCD swizzle so the 128 strip-blocks of
// one (b,h) stay on one XCD -> K/V panels fetched ~once per XCD, not 8x.
// Pbuf (P repack, phase 3) and xred (x reduction, epilogue) have disjoint
// lifetimes -> one union pool (36 KB instead of 68.6 KB), guarded by a barrier.
__global__ __launch_bounds__(512, 4) void attn_kernel(
    const bf16* __restrict__ qh, const bf16* __restrict__ kh,
    const bf16* __restrict__ vT, const float* __restrict__ posT,
    float* __restrict__ attn, bf16* __restrict__ xout) {
  __shared__ float smax[8][16];
  __shared__ float ssum[8][16];
  __shared__ __align__(16) char upool[8 * 16 * 136 * 2];  // 34816 B >= xred 32768 B
  auto Pbuf = reinterpret_cast<bf16(*)[16][136]>(upool);  // [8][16][136] bf16
  auto xred = reinterpret_cast<float(*)[16][64]>(upool);  // [8][16][64] f32

  const int tid = threadIdx.x;
  const int wv = tid >> 6, lane = tid & 63;
  const int r16 = lane & 15, quad = lane >> 4;

  // bijective XCD swizzle: 4096 blocks, 8 XCDs, 512 per XCD.
  const int bid = blockIdx.x;
  const int nbid = (bid & 7) * 512 + (bid >> 3);
  const int bh = nbid >> 7;          // 0..31
  const int strip = nbid & 127;      // 0..127
  const int b = bh >> 3, h = bh & 7;
  const int r0 = strip * 16;
  const int c0 = wv * 256;           // wave's 256-key chunk

  const bf16* qbase = qh + (size_t)bh * Sq * 64;
  const bf16* kbase = kh + (size_t)bh * Sq * 64;
  const bf16* vbase = vT + (size_t)bh * 64 * Sq;

  bfv8 aq0 = *(const bfv8*)(qbase + (size_t)(r0 + r16) * 64 + quad * 8);
  bfv8 aq1 = *(const bfv8*)(qbase + (size_t)(r0 + r16) * 64 + 32 + quad * 8);

  // ---- phase 1: raw scores (wave's 256 keys in 16 16x16 tiles) ----
  f32x4 acc[16];
#pragma unroll
  for (int t = 0; t < 16; t++) {
    const bf16* kp = kbase + (size_t)(c0 + t * 16 + r16) * 64 + quad * 8;
    bfv8 kb0 = *(const bfv8*)kp;
    bfv8 kb1 = *(const bfv8*)(kp + 32);
    f32x4 z = {0.f, 0.f, 0.f, 0.f};
    z = mfma16(aq0, kb0, z);
    z = mfma16(aq1, kb1, z);
    acc[t] = z;
  }

  // ---- phase 2: s = s/8 + pos; wave-local max ----
  float mx[4] = {-1e30f, -1e30f, -1e30f, -1e30f};
#pragma unroll
  for (int t = 0; t < 16; t++) {
    int colg = c0 + t * 16 + r16;
    f32x4 pk = *(const f32x4*)(posT + (size_t)colg * Sq + r0 + quad * 4);
#pragma unroll
    for (int r = 0; r < 4; r++) {
      float s = acc[t][r] * 0.125f + pk[r];
      acc[t][r] = s;
      mx[r] = fmaxf(mx[r], s);
    }
  }
#pragma unroll
  for (int m = 1; m < 16; m <<= 1)
#pragma unroll
    for (int r = 0; r < 4; r++) mx[r] = fmaxf(mx[r], __shfl_xor(mx[r], m, 64));

  // exp against the WAVE max; final rescale by exp(m_w - M)/S after one
  // combined (max,sum) LDS exchange -> single barrier instead of two.
  float sm[4] = {0.f, 0.f, 0.f, 0.f};
#pragma unroll
  for (int t = 0; t < 16; t++)
#pragma unroll
    for (int r = 0; r < 4; r++) {
      float e = __expf(acc[t][r] - mx[r]);
      acc[t][r] = e;
      sm[r] += e;
    }
#pragma unroll
  for (int m = 1; m < 16; m <<= 1)
#pragma unroll
    for (int r = 0; r < 4; r++) sm[r] += __shfl_xor(sm[r], m, 64);

  if (r16 == 0) {
#pragma unroll
    for (int r = 0; r < 4; r++) {
      smax[wv][quad * 4 + r] = mx[r];
      ssum[wv][quad * 4 + r] = sm[r];
    }
  }
  __syncthreads();

  float comb[4];
#pragma unroll
  for (int r = 0; r < 4; r++) {
    int row = quad * 4 + r;
    float M = smax[0][row];
#pragma unroll
    for (int w = 1; w < 8; w++) M = fmaxf(M, smax[w][row]);
    float S = 0.f;
#pragma unroll
    for (int w = 0; w < 8; w++) S += ssum[w][row] * __expf(smax[w][row] - M);
    comb[r] = __expf(mx[r] - M) / S;   // p = e * comb == exp(x - M) / S
  }

  // ---- phase 3: per 128-col chunk: fp32 attn store + bf16 repack + PV ----
  // NOTE: plain cached stores for attn.  Nontemporal stores were measured to
  // inflate hbm_bytes by ~380 MB (partial 64-B line writes skip the L2 merge
  // -> RMW at HBM).  L2 merges the two 64-B halves of each 128-B line here.
  f32x4 xacc[4] = {};
#pragma unroll
  for (int c = 0; c < 2; c++) {
#pragma unroll
    for (int tt = 0; tt < 8; tt++) {
      int t = c * 8 + tt;
      int colg = c0 + t * 16 + r16;
#pragma unroll
      for (int r = 0; r < 4; r++) {
        float p = acc[t][r] * comb[r];
        Pbuf[wv][quad * 4 + r][tt * 16 + r16] = (bf16)p;
        attn[((size_t)bh * Sq + r0 + quad * 4 + r) * Sq + colg] = p;
      }
    }
    // PV: x[16,64] += P[16,128] @ V[128,64]   (wave-private Pbuf, no barrier)
#pragma unroll
    for (int ks = 0; ks < 4; ks++) {
      bfv8 af = *(const bfv8*)&Pbuf[wv][r16][ks * 32 + quad * 8];
      int key0 = c0 + c * 128 + ks * 32;
#pragma unroll
      for (int nt = 0; nt < 4; nt++) {
        bfv8 bvv = *(const bfv8*)(vbase + (size_t)(nt * 16 + r16) * Sq + key0 + quad * 8);
        xacc[nt] = mfma16(af, bvv, xacc[nt]);
      }
    }
  }

  // ---- cross-wave x reduction -> x[B,S,D] (bf16 for the final GEMM) ----
  __syncthreads();  // all Pbuf reads done before xred overwrites the pool
#pragma unroll
  for (int nt = 0; nt < 4; nt++)
#pragma unroll
    for (int r = 0; r < 4; r++)
      xred[wv][quad * 4 + r][nt * 16 + r16] = xacc[nt][r];
  __syncthreads();
  {
    int row = tid >> 5, d2 = (tid & 31) * 2;   // 512 thr: 16 rows x 32 pairs
    f32x2 s = {0.f, 0.f};
#pragma unroll
    for (int w = 0; w < 8; w++) s += *(const f32x2*)&xred[w][row][d2];
    bfv2 o;
    o[0] = (bf16)s[0];
    o[1] = (bf16)s[1];
    *(bfv2*)(xout + ((size_t)(b * Sq + r0 + row)) * 512 + h * 64 + d2) = o;
  }
}

// ---------------------------------------------------------------------------
extern "C" void kernel_launch(void* const* d_in, const int* in_sizes, int n_in,
                              void* d_out, int out_size, void* d_ws,
                              size_t ws_size, hipStream_t stream) {
  const float* q    = (const float*)d_in[0];
  const float* k    = (const float*)d_in[1];
  const float* v    = (const float*)d_in[2];
  const int*   mask = (const int*)d_in[3];
  const float* pos  = (const float*)d_in[4];
  const float* lnw  = (const float*)d_in[5];
  const float* lnb  = (const float*)d_in[6];
  const float* Wq   = (const float*)d_in[7];
  const float* bq   = (const float*)d_in[8];
  const float* Wk   = (const float*)d_in[9];
  const float* bk   = (const float*)d_in[10];
  const float* Wv   = (const float*)d_in[11];
  const float* bv   = (const float*)d_in[12];
  const float* Wo   = (const float*)d_in[13];
  const float* bo   = (const float*)d_in[14];

  const size_t NE = (size_t)Bb * Sq * Dm;  // 4,194,304 (== S*S)
  if (ws_size < 64ull * 1024 * 1024) return;  // need exactly 64 MiB scratch

  // ws layout (64 MiB total):
  //   [ 0,16) MiB  posT  fp32 [S,S]
  //   [16,24) MiB  qn    bf16 [8192,512]   (aliased by xbuf after use)
  //   [24,32) MiB  kn    bf16
  //   [32,40) MiB  vn    bf16
  //   [40,48) MiB  qhp   bf16 [B,H,S,DK]
  //   [48,56) MiB  khp   bf16 [B,H,S,DK]
  //   [56,64) MiB  vhT   bf16 [B,H,DK,S]
  char* wsb = (char*)d_ws;
  float* posT = (float*)wsb;
  bf16* qn   = (bf16*)(wsb + 16ull * 1024 * 1024);
  bf16* kn   = (bf16*)(wsb + 24ull * 1024 * 1024);
  bf16* vn   = (bf16*)(wsb + 32ull * 1024 * 1024);
  bf16* qhp  = (bf16*)(wsb + 40ull * 1024 * 1024);
  bf16* khp  = (bf16*)(wsb + 48ull * 1024 * 1024);
  bf16* vhT  = (bf16*)(wsb + 56ull * 1024 * 1024);
  bf16* xbuf = qn;  // qn is dead once the Q projection GEMM has run

  float* out  = (float*)d_out;
  float* attn = out + NE;

  posT_kernel<<<dim3(Sq / 32, Sq / 32), 256, 0, stream>>>(pos, mask, posT);
  ln_kernel<<<dim3(BS / 4, 3), 256, 0, stream>>>(q, k, v, lnw, lnb, qn, kn, vn);
  gemm_proj<<<dim3(BS / 64, Dm / 64, 3), 256, 0, stream>>>(
      qn, kn, vn, Wq, Wk, Wv, bq, bk, bv, qhp, khp, vhT);
  attn_kernel<<<dim3((Sq / 16) * Hh * Bb), 512, 0, stream>>>(qhp, khp, vhT,
                                                             posT, attn, xbuf);
  gemm_bt<<<dim3(BS / 64, Dm / 64), 256, 0, stream>>>(xbuf, Wo, bo, nullptr, out, 2);
}

// Round 3
// 931.997 us; speedup vs baseline: 1.1111x; 1.0165x over previous
//
#include <hip/hip_runtime.h>

// ---------------------------------------------------------------------------
// MultiHeadAttention (fp32 I/O, bf16 MFMA compute):
//   LN -> {Q,K,V} proj -> softmax(QK^T/8 + pos, mask) -> attn (materialized,
//   fp32, part of d_out) -> PV -> out proj.
// B=4 H=8 S=2048 D=512 DK=64.  d_out = [out (B,S,D) | attn (B,H,S,S)] fp32.
// ---------------------------------------------------------------------------

typedef __bf16 bf16;
typedef __attribute__((ext_vector_type(8))) __bf16 bfv8;   // 16 B MFMA frag
typedef __attribute__((ext_vector_type(4))) __bf16 bfv4;   // 8 B
typedef __attribute__((ext_vector_type(2))) __bf16 bfv2;   // 4 B
typedef __attribute__((ext_vector_type(4))) float  f32x4;  // MFMA acc / 16 B
typedef __attribute__((ext_vector_type(2))) float  f32x2;  // 8 B

static constexpr int Dm = 512, Hh = 8, Sq = 2048, Bb = 4;
static constexpr int BS = Bb * Sq;                 // 8192 rows

__device__ __forceinline__ f32x4 mfma16(bfv8 a, bfv8 b, f32x4 c) {
  return __builtin_amdgcn_mfma_f32_16x16x32_bf16(a, b, c, 0, 0, 0);
}

// ------- K0: posS[i/16][j][i%15] strip-tiled masked pos -----------------------
// posS[((i>>4)*S + j)*16 + (i&15)] = mask[i][j] ? pos[i][j] : -1e30
// This is exactly the order the attention block (strip = i/16) consumes, so
// the per-tile pk load becomes one fully-coalesced 1-KB wave read instead of
// a 64-line gather (the round-2 latency bottleneck).
__global__ __launch_bounds__(256) void posS_kernel(
    const float* __restrict__ pos, const int* __restrict__ mask,
    float* __restrict__ posS) {
  __shared__ float tile[32][33];
  int i0 = blockIdx.y * 32, j0 = blockIdx.x * 32;
  int tx = threadIdx.x & 31, ty = threadIdx.x >> 5;  // 32 x 8
#pragma unroll
  for (int rr = 0; rr < 32; rr += 8) {
    int i = i0 + ty + rr, j = j0 + tx;
    float pv = pos[(size_t)i * Sq + j];
    int   mv = mask[(size_t)i * Sq + j];
    tile[ty + rr][tx] = mv ? pv : -1e30f;   // tile[i_local][j_local]
  }
  __syncthreads();
#pragma unroll
  for (int rr = 0; rr < 32; rr += 8) {
    int j = j0 + ty + rr, i = i0 + tx;
    posS[(size_t)((i >> 4) * Sq + j) * 16 + (i & 15)] = tile[tx][ty + rr];
  }
}

// ---------------- K1: LayerNorm (wave per row of 512), fp32 -> bf16 ----------
__global__ __launch_bounds__(256) void ln_kernel(
    const float* __restrict__ q, const float* __restrict__ k,
    const float* __restrict__ v, const float* __restrict__ w,
    const float* __restrict__ bia, bf16* __restrict__ qn,
    bf16* __restrict__ kn, bf16* __restrict__ vn) {
  int wv = threadIdx.x >> 6, lane = threadIdx.x & 63;
  int row = blockIdx.x * 4 + wv;  // 0..8191
  int which = blockIdx.y;
  const float* src = which == 0 ? q : (which == 1 ? k : v);
  bf16* dst        = which == 0 ? qn : (which == 1 ? kn : vn);

  f32x4 x0 = *(const f32x4*)(src + (size_t)row * Dm + lane * 8);
  f32x4 x1 = *(const f32x4*)(src + (size_t)row * Dm + lane * 8 + 4);
  float xf[8], s1 = 0.f, s2 = 0.f;
#pragma unroll
  for (int i = 0; i < 4; i++) { xf[i] = x0[i]; xf[4 + i] = x1[i]; }
#pragma unroll
  for (int i = 0; i < 8; i++) { s1 += xf[i]; s2 += xf[i] * xf[i]; }
#pragma unroll
  for (int m = 1; m < 64; m <<= 1) { s1 += __shfl_xor(s1, m, 64); s2 += __shfl_xor(s2, m, 64); }
  float mu = s1 * (1.0f / 512.0f);
  float var = s2 * (1.0f / 512.0f) - mu * mu;
  float rs = rsqrtf(var + 1e-5f);
  f32x4 w0 = *(const f32x4*)(w + lane * 8);
  f32x4 w1 = *(const f32x4*)(w + lane * 8 + 4);
  f32x4 b0 = *(const f32x4*)(bia + lane * 8);
  f32x4 b1 = *(const f32x4*)(bia + lane * 8 + 4);
  bfv8 o;
#pragma unroll
  for (int i = 0; i < 4; i++) {
    o[i]     = (bf16)((xf[i] - mu) * rs * w0[i] + b0[i]);
    o[4 + i] = (bf16)((xf[4 + i] - mu) * rs * w1[i] + b1[i]);
  }
  *(bfv8*)(dst + (size_t)row * Dm + lane * 8) = o;
}

// ---------------- shared GEMM body: C[m,n] = sum_k A[m,k]*W[n,k] + bias[n] ---
// A bf16 [M,512], W fp32 [N=512,512].  M=8192.
// mode 0: bf16 qh/kh [B,H,S,DK]; 1: bf16 vT [B,H,DK,S]; 2: fp32 out [M,512].
__device__ __forceinline__ void gemm_body(
    const bf16* __restrict__ A, const float* __restrict__ W,
    const float* __restrict__ bias, bf16* __restrict__ outb,
    float* __restrict__ outf, int mode, int m0, int n0) {
  __shared__ __align__(16) bf16 As[64][72];
  __shared__ __align__(16) bf16 Bs[64][72];
  int tid = threadIdx.x;
  int wv = tid >> 6, lane = tid & 63;
  int wm = (wv & 1) * 32, wn = (wv >> 1) * 32;
  int r16 = lane & 15, quad = lane >> 4;
  int lr = tid >> 2, sc = (tid & 3) * 16;

  f32x4 acc[2][2] = {};
  const bf16*  Ap = A + (size_t)(m0 + lr) * 512 + sc;
  const float* Wp = W + (size_t)(n0 + lr) * 512 + sc;

  for (int k0 = 0; k0 < 512; k0 += 64) {
    bfv8 a0 = *(const bfv8*)(Ap + k0);
    bfv8 a1 = *(const bfv8*)(Ap + k0 + 8);
    f32x4 w0 = *(const f32x4*)(Wp + k0);
    f32x4 w1 = *(const f32x4*)(Wp + k0 + 4);
    f32x4 w2 = *(const f32x4*)(Wp + k0 + 8);
    f32x4 w3 = *(const f32x4*)(Wp + k0 + 12);
    bfv8 bb0, bb1;
#pragma unroll
    for (int i = 0; i < 4; i++) {
      bb0[i] = (bf16)w0[i]; bb0[4 + i] = (bf16)w1[i];
      bb1[i] = (bf16)w2[i]; bb1[4 + i] = (bf16)w3[i];
    }
    __syncthreads();
    *(bfv8*)&As[lr][sc] = a0;  *(bfv8*)&As[lr][sc + 8] = a1;
    *(bfv8*)&Bs[lr][sc] = bb0; *(bfv8*)&Bs[lr][sc + 8] = bb1;
    __syncthreads();
#pragma unroll
    for (int kk = 0; kk < 2; kk++) {
      bfv8 af0 = *(const bfv8*)&As[wm + r16][kk * 32 + quad * 8];
      bfv8 af1 = *(const bfv8*)&As[wm + 16 + r16][kk * 32 + quad * 8];
      bfv8 bf0 = *(const bfv8*)&Bs[wn + r16][kk * 32 + quad * 8];
      bfv8 bf1 = *(const bfv8*)&Bs[wn + 16 + r16][kk * 32 + quad * 8];
      acc[0][0] = mfma16(af0, bf0, acc[0][0]);
      acc[0][1] = mfma16(af0, bf1, acc[0][1]);
      acc[1][0] = mfma16(af1, bf0, acc[1][0]);
      acc[1][1] = mfma16(af1, bf1, acc[1][1]);
    }
  }

#pragma unroll
  for (int nt = 0; nt < 2; nt++) {
    int n = n0 + wn + nt * 16 + r16;
    float bb = bias[n];
#pragma unroll
    for (int mt = 0; mt < 2; mt++) {
#pragma unroll
      for (int r = 0; r < 4; r++) {
        int m = m0 + wm + mt * 16 + quad * 4 + r;
        float o = acc[mt][nt][r] + bb;
        int bb_ = m >> 11, s = m & 2047, hh = n >> 6, dd = n & 63;
        if (mode == 0)
          outb[(((size_t)(bb_ * Hh + hh)) * Sq + s) * 64 + dd] = (bf16)o;
        else if (mode == 1)
          outb[(((size_t)(bb_ * Hh + hh)) * 64 + dd) * Sq + s] = (bf16)o;
        else
          outf[(size_t)m * 512 + n] = o;
      }
    }
  }
}

// ---- merged Q/K/V projection: blockIdx.z selects which projection ----------
__global__ __launch_bounds__(256) void gemm_proj(
    const bf16* __restrict__ qn, const bf16* __restrict__ kn,
    const bf16* __restrict__ vn, const float* __restrict__ Wq,
    const float* __restrict__ Wk, const float* __restrict__ Wv,
    const float* __restrict__ bq, const float* __restrict__ bk,
    const float* __restrict__ bv, bf16* __restrict__ qhp,
    bf16* __restrict__ khp, bf16* __restrict__ vhT) {
  int z = blockIdx.z;
  const bf16*  A    = z == 0 ? qn : (z == 1 ? kn : vn);
  const float* W    = z == 0 ? Wq : (z == 1 ? Wk : Wv);
  const float* bias = z == 0 ? bq : (z == 1 ? bk : bv);
  bf16*        outb = z == 0 ? qhp : (z == 1 ? khp : vhT);
  int mode = (z == 2) ? 1 : 0;
  gemm_body(A, W, bias, outb, nullptr, mode, blockIdx.x * 64, blockIdx.y * 64);
}

// ---- single GEMM (used for the output projection, mode 2) ------------------
__global__ __launch_bounds__(256) void gemm_bt(
    const bf16* __restrict__ A, const float* __restrict__ W,
    const float* __restrict__ bias, bf16* __restrict__ outb,
    float* __restrict__ outf, int mode) {
  gemm_body(A, W, bias, outb, outf, mode, blockIdx.x * 64, blockIdx.y * 64);
}

// ---------------- K3: attention: 16 q-rows x one (b,h) per block -------------
// 8 waves x 256 columns each (acc[16] = 64 regs/lane -> 4 waves/SIMD).
// posS gives coalesced pk loads; attn stores staged through LDS so every
// global store is a full-line 256-B-per-quad f32x4 burst (no partial-line RFO,
// which was ~255 MB of extra FETCH and a serialized store pipe in round 2).
__global__ __launch_bounds__(512, 4) void attn_kernel(
    const bf16* __restrict__ qh, const bf16* __restrict__ kh,
    const bf16* __restrict__ vT, const float* __restrict__ posS,
    float* __restrict__ attn, bf16* __restrict__ xout) {
  __shared__ float smax[8][16];
  __shared__ float ssum[8][16];
  __shared__ __align__(16) char upool[8 * 16 * 136 * 2];  // 34816 B >= xred 32768 B
  auto Pbuf = reinterpret_cast<bf16(*)[16][136]>(upool);  // [8][16][136] bf16
  auto xred = reinterpret_cast<float(*)[16][64]>(upool);  // [8][16][64] f32
  // fp32 store-staging: stride 68 floats -> quad row-offset 272 B = bank+16,
  // so the 4 quads' scalar writes land exactly 2-way per bank (free).
  __shared__ __align__(16) float Sst[8][16][68];          // 34816 B

  const int tid = threadIdx.x;
  const int wv = tid >> 6, lane = tid & 63;
  const int r16 = lane & 15, quad = lane >> 4;

  // bijective XCD swizzle: 4096 blocks, 8 XCDs, 512 per XCD.
  const int bid = blockIdx.x;
  const int nbid = (bid & 7) * 512 + (bid >> 3);
  const int bh = nbid >> 7;          // 0..31
  const int strip = nbid & 127;      // 0..127
  const int b = bh >> 3, h = bh & 7;
  const int r0 = strip * 16;
  const int c0 = wv * 256;           // wave's 256-key chunk

  const bf16* qbase = qh + (size_t)bh * Sq * 64;
  const bf16* kbase = kh + (size_t)bh * Sq * 64;
  const bf16* vbase = vT + (size_t)bh * 64 * Sq;
  const float* pbase = posS + (size_t)strip * Sq * 16;   // block's 128-KB slab

  bfv8 aq0 = *(const bfv8*)(qbase + (size_t)(r0 + r16) * 64 + quad * 8);
  bfv8 aq1 = *(const bfv8*)(qbase + (size_t)(r0 + r16) * 64 + 32 + quad * 8);

  // ---- phase 1: raw scores (wave's 256 keys in 16 16x16 tiles) ----
  f32x4 acc[16];
#pragma unroll
  for (int t = 0; t < 16; t++) {
    const bf16* kp = kbase + (size_t)(c0 + t * 16 + r16) * 64 + quad * 8;
    bfv8 kb0 = *(const bfv8*)kp;
    bfv8 kb1 = *(const bfv8*)(kp + 32);
    f32x4 z = {0.f, 0.f, 0.f, 0.f};
    z = mfma16(aq0, kb0, z);
    z = mfma16(aq1, kb1, z);
    acc[t] = z;
  }

  // ---- phase 2: s = s/8 + pos; wave-local max ----
  float mx[4] = {-1e30f, -1e30f, -1e30f, -1e30f};
#pragma unroll
  for (int t = 0; t < 16; t++) {
    int colg = c0 + t * 16 + r16;
    f32x4 pk = *(const f32x4*)(pbase + (size_t)colg * 16 + quad * 4);
#pragma unroll
    for (int r = 0; r < 4; r++) {
      float s = acc[t][r] * 0.125f + pk[r];
      acc[t][r] = s;
      mx[r] = fmaxf(mx[r], s);
    }
  }
#pragma unroll
  for (int m = 1; m < 16; m <<= 1)
#pragma unroll
    for (int r = 0; r < 4; r++) mx[r] = fmaxf(mx[r], __shfl_xor(mx[r], m, 64));

  // exp against the WAVE max; final rescale by exp(m_w - M)/S after one
  // combined (max,sum) LDS exchange -> single barrier instead of two.
  float sm[4] = {0.f, 0.f, 0.f, 0.f};
#pragma unroll
  for (int t = 0; t < 16; t++)
#pragma unroll
    for (int r = 0; r < 4; r++) {
      float e = __expf(acc[t][r] - mx[r]);
      acc[t][r] = e;
      sm[r] += e;
    }
#pragma unroll
  for (int m = 1; m < 16; m <<= 1)
#pragma unroll
    for (int r = 0; r < 4; r++) sm[r] += __shfl_xor(sm[r], m, 64);

  if (r16 == 0) {
#pragma unroll
    for (int r = 0; r < 4; r++) {
      smax[wv][quad * 4 + r] = mx[r];
      ssum[wv][quad * 4 + r] = sm[r];
    }
  }
  __syncthreads();

  float comb[4];
#pragma unroll
  for (int r = 0; r < 4; r++) {
    int row = quad * 4 + r;
    float M = smax[0][row];
#pragma unroll
    for (int w = 1; w < 8; w++) M = fmaxf(M, smax[w][row]);
    float S = 0.f;
#pragma unroll
    for (int w = 0; w < 8; w++) S += ssum[w][row] * __expf(smax[w][row] - M);
    comb[r] = __expf(mx[r] - M) / S;   // p = e * comb == exp(x - M) / S
  }

  // ---- phase 3: per 128-col chunk: staged attn store + bf16 repack + PV ----
  f32x4 xacc[4] = {};
#pragma unroll
  for (int c = 0; c < 2; c++) {
#pragma unroll
    for (int half = 0; half < 2; half++) {   // 64-col subchunk
#pragma unroll
      for (int tt4 = 0; tt4 < 4; tt4++) {
        int tt = half * 4 + tt4;
        int t = c * 8 + tt;
#pragma unroll
        for (int r = 0; r < 4; r++) {
          float p = acc[t][r] * comb[r];
          Pbuf[wv][quad * 4 + r][tt * 16 + r16] = (bf16)p;
          Sst[wv][quad * 4 + r][tt4 * 16 + r16] = p;
        }
      }
      // flush 16x64 fp32: each pass, a quad's 16 lanes write 256 contiguous B
      // (2 whole 128-B lines) -> no RFO.  Wave-private, no barrier needed.
      int colbase = c0 + c * 128 + half * 64;
#pragma unroll
      for (int pass = 0; pass < 4; pass++) {
        int row = pass * 4 + quad;
        f32x4 vv = *(const f32x4*)&Sst[wv][row][r16 * 4];
        *(f32x4*)(attn + ((size_t)bh * Sq + r0 + row) * Sq + colbase + r16 * 4) = vv;
      }
    }
    // PV: x[16,64] += P[16,128] @ V[128,64]   (wave-private Pbuf, no barrier)
#pragma unroll
    for (int ks = 0; ks < 4; ks++) {
      bfv8 af = *(const bfv8*)&Pbuf[wv][r16][ks * 32 + quad * 8];
      int key0 = c0 + c * 128 + ks * 32;
#pragma unroll
      for (int nt = 0; nt < 4; nt++) {
        bfv8 bvv = *(const bfv8*)(vbase + (size_t)(nt * 16 + r16) * Sq + key0 + quad * 8);
        xacc[nt] = mfma16(af, bvv, xacc[nt]);
      }
    }
  }

  // ---- cross-wave x reduction -> x[B,S,D] (bf16 for the final GEMM) ----
  __syncthreads();  // all Pbuf reads done before xred overwrites the pool
#pragma unroll
  for (int nt = 0; nt < 4; nt++)
#pragma unroll
    for (int r = 0; r < 4; r++)
      xred[wv][quad * 4 + r][nt * 16 + r16] = xacc[nt][r];
  __syncthreads();
  {
    int row = tid >> 5, d2 = (tid & 31) * 2;   // 512 thr: 16 rows x 32 pairs
    f32x2 s = {0.f, 0.f};
#pragma unroll
    for (int w = 0; w < 8; w++) s += *(const f32x2*)&xred[w][row][d2];
    bfv2 o;
    o[0] = (bf16)s[0];
    o[1] = (bf16)s[1];
    *(bfv2*)(xout + ((size_t)(b * Sq + r0 + row)) * 512 + h * 64 + d2) = o;
  }
}

// ---------------------------------------------------------------------------
extern "C" void kernel_launch(void* const* d_in, const int* in_sizes, int n_in,
                              void* d_out, int out_size, void* d_ws,
                              size_t ws_size, hipStream_t stream) {
  const float* q    = (const float*)d_in[0];
  const float* k    = (const float*)d_in[1];
  const float* v    = (const float*)d_in[2];
  const int*   mask = (const int*)d_in[3];
  const float* pos  = (const float*)d_in[4];
  const float* lnw  = (const float*)d_in[5];
  const float* lnb  = (const float*)d_in[6];
  const float* Wq   = (const float*)d_in[7];
  const float* bq   = (const float*)d_in[8];
  const float* Wk   = (const float*)d_in[9];
  const float* bk   = (const float*)d_in[10];
  const float* Wv   = (const float*)d_in[11];
  const float* bv   = (const float*)d_in[12];
  const float* Wo   = (const float*)d_in[13];
  const float* bo   = (const float*)d_in[14];

  const size_t NE = (size_t)Bb * Sq * Dm;  // 4,194,304 (== S*S)
  if (ws_size < 64ull * 1024 * 1024) return;  // need exactly 64 MiB scratch

  // ws layout (64 MiB total):
  //   [ 0,16) MiB  posS  fp32 [S/16][S][16]  (strip-tiled masked pos)
  //   [16,24) MiB  qn    bf16 [8192,512]   (aliased by xbuf after use)
  //   [24,32) MiB  kn    bf16
  //   [32,40) MiB  vn    bf16
  //   [40,48) MiB  qhp   bf16 [B,H,S,DK]
  //   [48,56) MiB  khp   bf16 [B,H,S,DK]
  //   [56,64) MiB  vhT   bf16 [B,H,DK,S]
  char* wsb = (char*)d_ws;
  float* posS = (float*)wsb;
  bf16* qn   = (bf16*)(wsb + 16ull * 1024 * 1024);
  bf16* kn   = (bf16*)(wsb + 24ull * 1024 * 1024);
  bf16* vn   = (bf16*)(wsb + 32ull * 1024 * 1024);
  bf16* qhp  = (bf16*)(wsb + 40ull * 1024 * 1024);
  bf16* khp  = (bf16*)(wsb + 48ull * 1024 * 1024);
  bf16* vhT  = (bf16*)(wsb + 56ull * 1024 * 1024);
  bf16* xbuf = qn;  // qn is dead once the Q projection GEMM has run

  float* out  = (float*)d_out;
  float* attn = out + NE;

  posS_kernel<<<dim3(Sq / 32, Sq / 32), 256, 0, stream>>>(pos, mask, posS);
  ln_kernel<<<dim3(BS / 4, 3), 256, 0, stream>>>(q, k, v, lnw, lnb, qn, kn, vn);
  gemm_proj<<<dim3(BS / 64, Dm / 64, 3), 256, 0, stream>>>(
      qn, kn, vn, Wq, Wk, Wv, bq, bk, bv, qhp, khp, vhT);
  attn_kernel<<<dim3((Sq / 16) * Hh * Bb), 512, 0, stream>>>(qhp, khp, vhT,
                                                             posS, attn, xbuf);
  gemm_bt<<<dim3(BS / 64, Dm / 64), 256, 0, stream>>>(xbuf, Wo, bo, nullptr, out, 2);
}